// Round 1
// baseline (26.385 us; speedup 1.0000x reference)
//
#include <hip/hip_runtime.h>

#define B_   128
#define IN_  1024
#define OUT_ 1024
#define NT   4            // output columns per block
#define KQ   8            // in-block K splits
#define KC   (IN_/KQ)     // 128 K per split

__global__ __launch_bounds__(1024, 1) void dendritic_kernel(
    const float* __restrict__ x,   // [128,1024]
    const float* __restrict__ Wn,  // W_nmda [1024,1024]
    const float* __restrict__ Wo,  // W_non  [1024,1024]
    const float* __restrict__ bo,  // b_non  [1024]
    float* __restrict__ out) {     // [128,1024]
  const int tid = threadIdx.x;
  const int m  = tid & (B_ - 1);
  const int kq = __builtin_amdgcn_readfirstlane(tid >> 7);  // wave-uniform
  const int n0 = blockIdx.x * NT;

  const float* xrow = x + m * IN_ + kq * KC;

  float accN[NT], accO[NT];
#pragma unroll
  for (int n = 0; n < NT; ++n) { accN[n] = 0.f; accO[n] = 0.f; }

  for (int c = 0; c < KC / 16; ++c) {           // 8 chunks of 16 floats
    float xr[16];
    const float4* xp = reinterpret_cast<const float4*>(xrow + c * 16);
    float4 v0 = xp[0], v1 = xp[1], v2 = xp[2], v3 = xp[3];
    xr[0]=v0.x; xr[1]=v0.y; xr[2]=v0.z; xr[3]=v0.w;
    xr[4]=v1.x; xr[5]=v1.y; xr[6]=v1.z; xr[7]=v1.w;
    xr[8]=v2.x; xr[9]=v2.y; xr[10]=v2.z; xr[11]=v2.w;
    xr[12]=v3.x; xr[13]=v3.y; xr[14]=v3.z; xr[15]=v3.w;
#pragma unroll
    for (int n = 0; n < NT; ++n) {
      // Wave-uniform addresses -> scalar loads, broadcast into v_fmac
      const float* wnp = Wn + (size_t)(n0 + n) * IN_ + kq * KC + c * 16;
      const float* wop = Wo + (size_t)(n0 + n) * IN_ + kq * KC + c * 16;
      float sN = 0.f, sO = 0.f;
#pragma unroll
      for (int j = 0; j < 16; ++j) {
        sN = fmaf(xr[j], wnp[j], sN);
        sO = fmaf(xr[j], wop[j], sO);
      }
      accN[n] += sN;
      accO[n] += sO;
    }
  }

  // in-block K reduction
  __shared__ float red[KQ][B_][2 * NT];  // 32 KiB
#pragma unroll
  for (int n = 0; n < NT; ++n) {
    red[kq][m][n]      = accN[n];
    red[kq][m][NT + n] = accO[n];
  }
  __syncthreads();

  if (kq == 0) {
#pragma unroll
    for (int n = 0; n < NT; ++n) {
      float zN = 0.f, zO = 0.f;
#pragma unroll
      for (int q = 0; q < KQ; ++q) { zN += red[q][m][n]; zO += red[q][m][NT + n]; }
      const int gn = n0 + n;
      // conv1d([0.5,0.5], valid) sum == full dot minus half the two edge terms
      zN -= 0.5f * (x[m * IN_] * Wn[(size_t)gn * IN_] +
                    x[m * IN_ + IN_ - 1] * Wn[(size_t)gn * IN_ + IN_ - 1]);
      const float zb    = zO + bo[gn];
      const float state = 1.f / (1.f + expf(-zb)) - 1.f;   // in (-1,0)
      const float ca    = fmaxf(zN, 0.f);
      const float nm    = 2.f + state;                     // in (1,2)
      const float kd    = exp2f(-nm);                      // 0.5^nm
      const float xn    = (ca > 0.f) ? exp2f(nm * log2f(ca)) : 0.f;
      out[m * OUT_ + gn] = xn / (kd + xn) + state;
    }
  }
}

extern "C" void kernel_launch(void* const* d_in, const int* in_sizes, int n_in,
                              void* d_out, int out_size, void* d_ws, size_t ws_size,
                              hipStream_t stream) {
  const float* x  = (const float*)d_in[0];   // inputs  [128,1024]
  const float* Wn = (const float*)d_in[1];   // W_nmda  [1024,1024]
  const float* Wo = (const float*)d_in[2];   // W_non   [1024,1024]
  const float* bo = (const float*)d_in[3];   // b_non   [1024]
  float* out = (float*)d_out;
  dendritic_kernel<<<dim3(OUT_ / NT), dim3(1024), 0, stream>>>(x, Wn, Wo, bo, out);
}

// Round 2
// 14.315 us; speedup vs baseline: 1.8432x; 1.8432x over previous
//
#include <hip/hip_runtime.h>

#define B_   128
#define IN_  1024
#define OUT_ 1024

typedef _Float16 f16x8 __attribute__((ext_vector_type(8)));
typedef float    f32x4 __attribute__((ext_vector_type(4)));

// grid: 256 blocks = 4 mq (32 rows each) x 64 ng (16 cols each, both GEMMs)
// block: 512 threads = 8 waves; wave w owns K-slice [w*128, w*128+128)
__global__ __launch_bounds__(512, 2) void dendritic_mfma(
    const float* __restrict__ x,   // [128,1024]
    const float* __restrict__ Wn,  // [1024,1024]
    const float* __restrict__ Wo,  // [1024,1024]
    const float* __restrict__ bo,  // [1024]
    float* __restrict__ out) {     // [128,1024]
  const int tid = threadIdx.x;
  const int w   = tid >> 6;        // wave id 0..7
  const int l   = tid & 63;        // lane
  const int b   = blockIdx.x;
  const int ng  = b & 63;          // n-group
  const int mq  = b >> 6;          // m-quarter
  const int n0  = ng * 16;
  const int m0  = mq * 32;

  const int row = l & 15;          // fragment row/col index
  const int kq4 = l >> 4;          // k-quadrant 0..3
  const int kbase = w * 128;

  f32x4 acc00 = {0.f,0.f,0.f,0.f}, acc01 = {0.f,0.f,0.f,0.f};
  f32x4 acc10 = {0.f,0.f,0.f,0.f}, acc11 = {0.f,0.f,0.f,0.f};

#pragma unroll
  for (int ks = 0; ks < 4; ++ks) {
    const int k = kbase + ks * 32 + kq4 * 8;   // lane's 8 contiguous K elems
    const float4* pa0 = (const float4*)(x  + (size_t)(m0 + row)      * IN_ + k);
    const float4* pa1 = (const float4*)(x  + (size_t)(m0 + 16 + row) * IN_ + k);
    const float4* pb0 = (const float4*)(Wn + (size_t)(n0 + row)      * IN_ + k);
    const float4* pb1 = (const float4*)(Wo + (size_t)(n0 + row)      * IN_ + k);
    float4 a0u = pa0[0], a0v = pa0[1];
    float4 a1u = pa1[0], a1v = pa1[1];
    float4 b0u = pb0[0], b0v = pb0[1];
    float4 b1u = pb1[0], b1v = pb1[1];
    f16x8 af0 = { (_Float16)a0u.x,(_Float16)a0u.y,(_Float16)a0u.z,(_Float16)a0u.w,
                  (_Float16)a0v.x,(_Float16)a0v.y,(_Float16)a0v.z,(_Float16)a0v.w };
    f16x8 af1 = { (_Float16)a1u.x,(_Float16)a1u.y,(_Float16)a1u.z,(_Float16)a1u.w,
                  (_Float16)a1v.x,(_Float16)a1v.y,(_Float16)a1v.z,(_Float16)a1v.w };
    f16x8 bf0 = { (_Float16)b0u.x,(_Float16)b0u.y,(_Float16)b0u.z,(_Float16)b0u.w,
                  (_Float16)b0v.x,(_Float16)b0v.y,(_Float16)b0v.z,(_Float16)b0v.w };
    f16x8 bf1 = { (_Float16)b1u.x,(_Float16)b1u.y,(_Float16)b1u.z,(_Float16)b1u.w,
                  (_Float16)b1v.x,(_Float16)b1v.y,(_Float16)b1v.z,(_Float16)b1v.w };
    acc00 = __builtin_amdgcn_mfma_f32_16x16x32_f16(af0, bf0, acc00, 0, 0, 0);
    acc01 = __builtin_amdgcn_mfma_f32_16x16x32_f16(af0, bf1, acc01, 0, 0, 0);
    acc10 = __builtin_amdgcn_mfma_f32_16x16x32_f16(af1, bf0, acc10, 0, 0, 0);
    acc11 = __builtin_amdgcn_mfma_f32_16x16x32_f16(af1, bf1, acc11, 0, 0, 0);
  }

  // K-reduction across the 8 waves, then fused epilogue.
  __shared__ f32x4 red[8][2][2][64];   // [wave][mt][gemm][lane] = 32 KiB
  red[w][0][0][l] = acc00;
  red[w][0][1][l] = acc01;
  red[w][1][0][l] = acc10;
  red[w][1][1][l] = acc11;
  __syncthreads();

  if (tid < 128) {
    const int mt = tid >> 6;
    const int ll = tid & 63;
    f32x4 sN = red[0][mt][0][ll];
    f32x4 sO = red[0][mt][1][ll];
#pragma unroll
    for (int q = 1; q < 8; ++q) { sN += red[q][mt][0][ll]; sO += red[q][mt][1][ll]; }

    const int col = ll & 15;
    const int n   = n0 + col;
    const float bias = bo[n];
    const float wn0  = Wn[(size_t)n * IN_];
    const float wnL  = Wn[(size_t)n * IN_ + IN_ - 1];
#pragma unroll
    for (int r = 0; r < 4; ++r) {
      const int m = m0 + mt * 16 + (ll >> 4) * 4 + r;
      // conv1d([.5,.5], valid).sum == full dot - half the two edge terms (exact f32)
      const float zN = sN[r] - 0.5f * (x[(size_t)m * IN_] * wn0 +
                                       x[(size_t)m * IN_ + IN_ - 1] * wnL);
      const float zO = sO[r] + bias;
      const float state = 1.f / (1.f + expf(-zO)) - 1.f;   // (-1,0)
      const float nm    = 2.f + state;                     // (1,2)
      const float kd    = exp2f(-nm);                      // 0.5^nm
      const float ca    = fmaxf(zN, 0.f);
      const float xn    = (ca > 0.f) ? exp2f(nm * log2f(ca)) : 0.f;
      out[(size_t)m * OUT_ + n] = xn / (kd + xn) + state;
    }
  }
}

extern "C" void kernel_launch(void* const* d_in, const int* in_sizes, int n_in,
                              void* d_out, int out_size, void* d_ws, size_t ws_size,
                              hipStream_t stream) {
  const float* x  = (const float*)d_in[0];
  const float* Wn = (const float*)d_in[1];
  const float* Wo = (const float*)d_in[2];
  const float* bo = (const float*)d_in[3];
  float* out = (float*)d_out;
  dendritic_mfma<<<dim3(256), dim3(512), 0, stream>>>(x, Wn, Wo, bo, out);
}